// Round 1
// baseline (335.273 us; speedup 1.0000x reference)
//
#include <hip/hip_runtime.h>
#include <math.h>

// Problem constants (fixed by reference setup_inputs)
constexpr int B = 2, C = 16, H = 160, W = 192, S = 3, D = 48;
constexpr int HW = H * W;
constexpr int ND = 4;          // depth hypotheses per thread
constexpr int G = D / ND;      // depth groups

// ------------------------------------------------------------------
// Setup kernel: per (s,b) fold the full projection chain into
//   A = Ks * R * inv(Kref)  (3x3, f64)   q = Ks * t  (3, f64)
// so the main kernel does p = depth*(A*[u,v,1]) + q.
// ws layout: (s*B+b)*12 doubles = [A row-major 0..8][q 9..11]
// ------------------------------------------------------------------
__global__ void precompute_mats(const float* __restrict__ ref_intr,
                                const float* __restrict__ src_intr,
                                const float* __restrict__ ref_to_src,
                                double* __restrict__ ws)
{
    const int i = threadIdx.x;
    if (i >= S * B) return;
    const int b = i % B;

    // f64 adjugate inverse of ref intrinsics
    const float* Kp = ref_intr + b * 9;
    const double a00 = Kp[0], a01 = Kp[1], a02 = Kp[2];
    const double a10 = Kp[3], a11 = Kp[4], a12 = Kp[5];
    const double a20 = Kp[6], a21 = Kp[7], a22 = Kp[8];
    const double c00 =  (a11 * a22 - a12 * a21);
    const double c01 = -(a10 * a22 - a12 * a20);
    const double c02 =  (a10 * a21 - a11 * a20);
    const double c10 = -(a01 * a22 - a02 * a21);
    const double c11 =  (a00 * a22 - a02 * a20);
    const double c12 = -(a00 * a21 - a01 * a20);
    const double c20 =  (a01 * a12 - a02 * a11);
    const double c21 = -(a00 * a12 - a02 * a10);
    const double c22 =  (a00 * a11 - a01 * a10);
    const double invdet = 1.0 / (a00 * c00 + a01 * c01 + a02 * c02);
    const double iK[9] = { c00 * invdet, c10 * invdet, c20 * invdet,
                           c01 * invdet, c11 * invdet, c21 * invdet,
                           c02 * invdet, c12 * invdet, c22 * invdet };

    const float* Tp = ref_to_src + i * 16;  // 4x4 row-major
    const float* Ks = src_intr + i * 9;

    double M[9];  // R * inv(K)
    #pragma unroll
    for (int r = 0; r < 3; ++r)
        #pragma unroll
        for (int c = 0; c < 3; ++c)
            M[r * 3 + c] = (double)Tp[r * 4 + 0] * iK[0 + c]
                         + (double)Tp[r * 4 + 1] * iK[3 + c]
                         + (double)Tp[r * 4 + 2] * iK[6 + c];

    double* o = ws + i * 12;
    #pragma unroll
    for (int r = 0; r < 3; ++r) {
        #pragma unroll
        for (int c = 0; c < 3; ++c)
            o[r * 3 + c] = (double)Ks[r * 3 + 0] * M[0 + c]
                         + (double)Ks[r * 3 + 1] * M[3 + c]
                         + (double)Ks[r * 3 + 2] * M[6 + c];
        o[9 + r] = (double)Ks[r * 3 + 0] * (double)Tp[3]
                 + (double)Ks[r * 3 + 1] * (double)Tp[7]
                 + (double)Ks[r * 3 + 2] * (double)Tp[11];
    }
}

// ------------------------------------------------------------------
// Main kernel: one thread = one pixel x ND depths.
// Geometry stays f64 (f32 geometry failed at 5.7e-2 in prior session),
// but slimmed: 3 f64 FMA + rcp-Newton + floor per (s,depth).
// ------------------------------------------------------------------
__global__ __launch_bounds__(256) void plane_sweep_kernel(
    const float* __restrict__ ref_feats,   // [B,C,H,W]
    const float* __restrict__ src_feats,   // [S,B,C,H,W]
    const float* __restrict__ depths,      // [D]
    const double* __restrict__ ws,         // [S*B][12]
    float* __restrict__ out)               // [B,D,H,W]
{
    const int idx = blockIdx.x * blockDim.x + threadIdx.x;
    const int total = B * G * HW;
    if (idx >= total) return;

    const int w  = idx % W;
    const int h  = (idx / W) % H;
    const int dg = (idx / HW) % G;   // uniform per block (HW*G % 256 == 0)
    const int b  = idx / (HW * G);   // uniform per block

    // ---- ref fragment: load, zero-mean, norm (f32, well-conditioned) ----
    float f1[C];
    const float* rp = ref_feats + (b * C) * HW + h * W + w;
    float sum1 = 0.0f;
    #pragma unroll
    for (int c = 0; c < C; ++c) { f1[c] = rp[c * HW]; sum1 += f1[c]; }
    const float m1 = sum1 * (1.0f / C);
    float sq1 = 0.0f;
    #pragma unroll
    for (int c = 0; c < C; ++c) { f1[c] -= m1; sq1 = fmaf(f1[c], f1[c], sq1); }
    const float n1 = sqrtf(sq1);

    // ---- per-source rays (depth-independent), computed once ----
    const double u = (double)w, v = (double)h;
    double rx[S], ry[S], rz[S], q0[S], q1[S], q2[S];
    #pragma unroll
    for (int s = 0; s < S; ++s) {
        const double* Aq = ws + (s * B + b) * 12;   // wave-uniform -> scalar loads
        rx[s] = Aq[0] * u + Aq[1] * v + Aq[2];
        ry[s] = Aq[3] * u + Aq[4] * v + Aq[5];
        rz[s] = Aq[6] * u + Aq[7] * v + Aq[8];
        q0[s] = Aq[9]; q1[s] = Aq[10]; q2[s] = Aq[11];
    }

    float* op = out + (size_t)((b * D + dg * ND) * HW + h * W + w);

    #pragma unroll 1          // keep cost/depth scalar; body already has 192-load ILP
    for (int j = 0; j < ND; ++j) {
        const double depth = (double)depths[dg * ND + j];  // uniform -> scalar load
        float cost = 0.0f;

        #pragma unroll        // static indexing into rx[]/ry[]/...
        for (int s = 0; s < S; ++s) {
            const double p0 = fma(depth, rx[s], q0[s]);
            const double p1 = fma(depth, ry[s], q1[s]);
            const double p2 = fma(depth, rz[s], q2[s]);

            const bool valid = p2 > 0.001;
            const double zs = fmax(p2, 0.001);
            // f64 reciprocal: v_rcp approx + 2 Newton steps (rel err ~1e-16),
            // far cheaper than the IEEE f64 div chain.
#if __has_builtin(__builtin_amdgcn_rcp)
            double r = __builtin_amdgcn_rcp(zs);
#else
            double r = (double)__builtin_amdgcn_rcpf((float)zs);
#endif
            r = r * fma(-zs, r, 2.0);
            r = r * fma(-zs, r, 2.0);
            const double x = p0 * r;
            const double y = p1 * r;

            const double x0f = floor(x);
            const double y0f = floor(y);
            const double fx = x - x0f;
            const double fy = y - y0f;
            const int x0 = (int)x0f;
            const int y0 = (int)y0f;
            const int x1 = x0 + 1;
            const int y1 = y0 + 1;

            // weights in f64, rounded to f32 (matches prior validated approach)
            const double gx = 1.0 - fx, gy = 1.0 - fy;
            const bool okx0 = (x0 >= 0) & (x0 < W);
            const bool okx1 = (x1 >= 0) & (x1 < W);
            const bool oky0 = (y0 >= 0) & (y0 < H);
            const bool oky1 = (y1 >= 0) & (y1 < H);
            const float w00 = (float)((valid & okx0 & oky0) ? gx * gy : 0.0);
            const float w01 = (float)((valid & okx1 & oky0) ? fx * gy : 0.0);
            const float w10 = (float)((valid & okx0 & oky1) ? gx * fy : 0.0);
            const float w11 = (float)((valid & okx1 & oky1) ? fx * fy : 0.0);

            const int x0c = min(max(x0, 0), W - 1);
            const int x1c = min(max(x1, 0), W - 1);
            const int y0c = min(max(y0, 0), H - 1);
            const int y1c = min(max(y1, 0), H - 1);
            const int off00 = y0c * W + x0c;
            const int off01 = y0c * W + x1c;
            const int off10 = y1c * W + x0c;
            const int off11 = y1c * W + x1c;

            const float* base = src_feats + ((size_t)(s * B + b) * C) * HW;

            // pass 1: bilinear + sum (f32)
            float f2[C];
            float sum2 = 0.0f;
            #pragma unroll
            for (int c = 0; c < C; ++c) {
                const float* p = base + c * HW;
                const float v00 = p[off00];
                const float v01 = p[off01];
                const float v10 = p[off10];
                const float v11 = p[off11];
                const float val = w00 * v00 + w01 * v01 + w10 * v10 + w11 * v11;
                f2[c] = val;
                sum2 += val;
            }
            // pass 2: mean-subtracted NCC reduction (f32).
            // Two-pass kept deliberately: single-pass sq2 = E[x^2]-E[x]^2
            // cancels catastrophically at the ill-conditioned (n2 ~ 7e-4) pixels.
            const float m2 = sum2 * (1.0f / C);
            float sq2 = 0.0f;
            float dot = 0.0f;
            #pragma unroll
            for (int c = 0; c < C; ++c) {
                const float f2c = f2[c] - m2;
                sq2 = fmaf(f2c, f2c, sq2);
                dot = fmaf(f1[c], f2c, dot);
            }
            const float den = n1 * sqrtf(sq2) + 1e-6f;
            cost += dot / den;
        }

        op[j * HW] = cost * (1.0f / S);
    }
}

extern "C" void kernel_launch(void* const* d_in, const int* in_sizes, int n_in,
                              void* d_out, int out_size, void* d_ws, size_t ws_size,
                              hipStream_t stream) {
    const float* ref_feats  = (const float*)d_in[0];
    const float* src_feats  = (const float*)d_in[1];
    const float* ref_intr   = (const float*)d_in[2];
    const float* src_intr   = (const float*)d_in[3];
    const float* ref_to_src = (const float*)d_in[4];
    const float* depths     = (const float*)d_in[5];
    float* out = (float*)d_out;
    double* ws = (double*)d_ws;   // needs S*B*12*8 = 576 bytes

    precompute_mats<<<1, 64, 0, stream>>>(ref_intr, src_intr, ref_to_src, ws);

    const int total = B * G * HW;
    const int block = 256;
    const int grid = (total + block - 1) / block;
    plane_sweep_kernel<<<grid, block, 0, stream>>>(
        ref_feats, src_feats, depths, ws, out);
}